// Round 1
// baseline (1302.557 us; speedup 1.0000x reference)
//
#include <hip/hip_runtime.h>
#include <hip/hip_bf16.h>
#include <math.h>

// ---------------------------------------------------------------------------
// VQ-VAE vector quantizer, fp32.
// z_e: [N=32768, D=256] f32, embedding: [K=4096, D=256] f32
// outputs (concatenated f32 in d_out):
//   z_q   [N*256]  gathered codes
//   idx   [N]      argmin indices stored as float values
//   ppl   [1]      perplexity
// ---------------------------------------------------------------------------

#define DIM   256
#define BM    64     // rows per block
#define BKC   128    // codes per k-tile
#define DC    32     // d-chunk
#define LD    36     // padded LDS stride (words)

// ||e_k||^2, one 64-thread block per code
__global__ void vq_e2(const float* __restrict__ emb, float* __restrict__ e2) {
    int k = blockIdx.x;
    int l = threadIdx.x;
    float4 v = ((const float4*)(emb + (size_t)k * DIM))[l];
    float s = v.x * v.x + v.y * v.y + v.z * v.z + v.w * v.w;
    #pragma unroll
    for (int off = 32; off; off >>= 1) s += __shfl_xor(s, off);
    if (l == 0) e2[k] = s;
}

__global__ void vq_zero(int* __restrict__ p, int n) {
    int i = blockIdx.x * blockDim.x + threadIdx.x;
    if (i < n) p[i] = 0;
}

// fused distance GEMM + argmin.
// block: 256 threads = 16x16; each thread owns 4 rows x 8 codes.
__global__ __launch_bounds__(256, 2) void vq_argmin(
    const float* __restrict__ z, const float* __restrict__ emb,
    const float* __restrict__ e2, float* __restrict__ idxf, int K)
{
    __shared__ float zs[BM * LD];    // 9216 B
    __shared__ float es[BKC * LD];   // 18432 B

    const int t  = threadIdx.x;
    const int tx = t & 15;
    const int ty = t >> 4;
    const int rowbase = blockIdx.x * BM;
    const float* zbase = z + (size_t)rowbase * DIM;

    float best[4];
    int   bidx[4];
    #pragma unroll
    for (int i = 0; i < 4; ++i) { best[i] = 3.4e38f; bidx[i] = 0; }

    for (int kt = 0; kt < K; kt += BKC) {
        float acc[4][8];
        #pragma unroll
        for (int i = 0; i < 4; ++i)
            #pragma unroll
            for (int j = 0; j < 8; ++j) acc[i][j] = 0.0f;

        for (int dc = 0; dc < DIM; dc += DC) {
            // stage Z tile: 64 rows x 32 cols (8 floats / thread)
            {
                int lr = t >> 2;
                int o  = (t & 3) * 8;
                const float* gp = zbase + (size_t)lr * DIM + dc + o;
                float4 a = *(const float4*)gp;
                float4 b = *(const float4*)(gp + 4);
                *(float4*)&zs[lr * LD + o]     = a;
                *(float4*)&zs[lr * LD + o + 4] = b;
            }
            // stage E tile: 128 rows x 32 cols (16 floats / thread)
            {
                int lc = t >> 1;
                int o  = (t & 1) * 16;
                const float* gp = emb + (size_t)(kt + lc) * DIM + dc + o;
                float4 a = *(const float4*)gp;
                float4 b = *(const float4*)(gp + 4);
                float4 c4 = *(const float4*)(gp + 8);
                float4 d4 = *(const float4*)(gp + 12);
                *(float4*)&es[lc * LD + o]      = a;
                *(float4*)&es[lc * LD + o + 4]  = b;
                *(float4*)&es[lc * LD + o + 8]  = c4;
                *(float4*)&es[lc * LD + o + 12] = d4;
            }
            __syncthreads();

            const float* zp = &zs[(ty * 4) * LD];
            const float* ep = &es[tx * LD];
            #pragma unroll
            for (int d = 0; d < DC; d += 4) {
                float4 zv[4], ev[8];
                #pragma unroll
                for (int i = 0; i < 4; ++i) zv[i] = *(const float4*)&zp[i * LD + d];
                #pragma unroll
                for (int j = 0; j < 8; ++j) ev[j] = *(const float4*)&ep[j * 16 * LD + d];
                #pragma unroll
                for (int i = 0; i < 4; ++i)
                    #pragma unroll
                    for (int j = 0; j < 8; ++j) {
                        acc[i][j] += zv[i].x * ev[j].x;
                        acc[i][j] += zv[i].y * ev[j].y;
                        acc[i][j] += zv[i].z * ev[j].z;
                        acc[i][j] += zv[i].w * ev[j].w;
                    }
            }
            __syncthreads();
        }

        // finalize this code tile
        #pragma unroll
        for (int j = 0; j < 8; ++j) {
            int c = kt + tx + 16 * j;
            float ev2 = e2[c];
            #pragma unroll
            for (int i = 0; i < 4; ++i) {
                float dist = ev2 - 2.0f * acc[i][j];
                if (dist < best[i] || (dist == best[i] && c < bidx[i])) {
                    best[i] = dist; bidx[i] = c;
                }
            }
        }
    }

    // reduce argmin across the 16 tx lanes (contiguous within the wave)
    #pragma unroll
    for (int i = 0; i < 4; ++i) {
        float bd = best[i];
        int   bi = bidx[i];
        #pragma unroll
        for (int off = 8; off; off >>= 1) {
            float od = __shfl_xor(bd, off);
            int   oi = __shfl_xor(bi, off);
            if (od < bd || (od == bd && oi < bi)) { bd = od; bi = oi; }
        }
        if (tx == 0) idxf[rowbase + ty * 4 + i] = (float)bi;
    }
}

// z_q[n,:] = emb[idx[n],:]; 4 rows per 256-thread block
__global__ void vq_gather(const float* __restrict__ emb,
                          const float* __restrict__ idxf,
                          float* __restrict__ zq, int N)
{
    int n = blockIdx.x * 4 + (threadIdx.x >> 6);
    int l = threadIdx.x & 63;
    if (n >= N) return;
    int idx = (int)idxf[n];
    float4 v = ((const float4*)(emb + (size_t)idx * DIM))[l];
    ((float4*)(zq + (size_t)n * DIM))[l] = v;
}

__global__ void vq_hist(const float* __restrict__ idxf, int* __restrict__ counts, int N) {
    int n = blockIdx.x * blockDim.x + threadIdx.x;
    if (n < N) atomicAdd(&counts[(int)idxf[n]], 1);
}

__global__ void vq_ppl(const int* __restrict__ counts, float invN,
                       float* __restrict__ out, int K)
{
    int t = threadIdx.x;
    float s = 0.0f;
    for (int k = t; k < K; k += 256) {
        float p = (float)counts[k] * invN;
        s += p * logf(p + 1e-10f);
    }
    #pragma unroll
    for (int off = 32; off; off >>= 1) s += __shfl_xor(s, off);
    __shared__ float wsum[4];
    if ((t & 63) == 0) wsum[t >> 6] = s;
    __syncthreads();
    if (t == 0) out[0] = expf(-(wsum[0] + wsum[1] + wsum[2] + wsum[3]));
}

extern "C" void kernel_launch(void* const* d_in, const int* in_sizes, int n_in,
                              void* d_out, int out_size, void* d_ws, size_t ws_size,
                              hipStream_t stream)
{
    const float* z   = (const float*)d_in[0];
    const float* emb = (const float*)d_in[1];
    const int N = in_sizes[0] / DIM;   // 32768
    const int K = in_sizes[1] / DIM;   // 4096

    float* out  = (float*)d_out;
    float* zq   = out;
    float* idxf = out + (size_t)N * DIM;
    float* ppl  = idxf + N;

    float* e2     = (float*)d_ws;
    int*   counts = (int*)((char*)d_ws + (size_t)K * sizeof(float));

    vq_e2<<<K, 64, 0, stream>>>(emb, e2);
    vq_zero<<<(K + 255) / 256, 256, 0, stream>>>(counts, K);
    vq_argmin<<<N / BM, 256, 0, stream>>>(z, emb, e2, idxf, K);
    vq_gather<<<N / 4, 256, 0, stream>>>(emb, idxf, zq, N);
    vq_hist<<<(N + 255) / 256, 256, 0, stream>>>(idxf, counts, N);
    vq_ppl<<<1, 256, 0, stream>>>(counts, 1.0f / (float)N, ppl, K);
}

// Round 2
// 380.885 us; speedup vs baseline: 3.4198x; 3.4198x over previous
//
#include <hip/hip_runtime.h>
#include <hip/hip_bf16.h>
#include <math.h>
#include <stdint.h>

typedef _Float16 f16;
typedef _Float16 f16x8 __attribute__((ext_vector_type(8)));
typedef float f32x4 __attribute__((ext_vector_type(4)));

#define DIM 256
#define RB 32      // rows per argmin2 block
#define CT 128     // codes per tile
#define BK 64      // depth chunk
#define LOSCALE 2048.0f
#define INV_LOSCALE (1.0f/2048.0f)

// ---------------------------------------------------------------------------
// prep: split embedding into f16 hi + scaled f16 lo (lo' = (e-hi)*2048).
// e ~= hi + lo'/2048 to ~2^-23 relative; all f16 values in normal range.
// ---------------------------------------------------------------------------
__global__ void vq_pack(const float* __restrict__ emb,
                        f16* __restrict__ eh, f16* __restrict__ el)
{
    int gid = blockIdx.x * blockDim.x + threadIdx.x;   // one per 8 elements
    int k  = gid >> 5;
    int d0 = (gid & 31) * 8;
    const float* gp = emb + (size_t)k * DIM + d0;
    float4 x0 = *(const float4*)gp;
    float4 x1 = *(const float4*)(gp + 4);
    float xs[8] = {x0.x, x0.y, x0.z, x0.w, x1.x, x1.y, x1.z, x1.w};
    f16x8 hi, lo;
    #pragma unroll
    for (int j = 0; j < 8; ++j) {
        f16 h = (f16)xs[j];
        float r = xs[j] - (float)h;
        hi[j] = h;
        lo[j] = (f16)(r * LOSCALE);
    }
    *(f16x8*)(eh + (size_t)k * DIM + d0) = hi;
    *(f16x8*)(el + (size_t)k * DIM + d0) = lo;
}

// ||e_k||^2, one 64-thread block per code (fp32, full precision)
__global__ void vq_e2(const float* __restrict__ emb, float* __restrict__ e2) {
    int k = blockIdx.x;
    int l = threadIdx.x;
    float4 v = ((const float4*)(emb + (size_t)k * DIM))[l];
    float s = v.x * v.x + v.y * v.y + v.z * v.z + v.w * v.w;
    #pragma unroll
    for (int off = 32; off; off >>= 1) s += __shfl_xor(s, off);
    if (l == 0) e2[k] = s;
}

__global__ void vq_zero(int* __restrict__ p, int n) {
    int i = blockIdx.x * blockDim.x + threadIdx.x;
    if (i < n) p[i] = 0;
}

// ---------------------------------------------------------------------------
// MFMA distance GEMM + fused argmin.
// Block: 256 thr (4 waves), 32 z-rows resident (hi/lo f16, XOR-swizzled LDS),
// sweeps all 4096 codes in 128-code tiles x 64-depth chunks.
// dot = acc0 + acc1/2048  where acc0 = zh.eh, acc1 = zh.el' + zl'.eh.
// argmin key: monotonic-u32(dist)<<32 | code  (exact smaller-index ties).
// ---------------------------------------------------------------------------
__global__ __launch_bounds__(256, 2) void vq_argmin2(
    const float* __restrict__ z, const f16* __restrict__ eh,
    const f16* __restrict__ el, const float* __restrict__ e2,
    float* __restrict__ idxf)
{
    __shared__ __align__(16) char As_h[RB * DIM * 2];   // 16 KB
    __shared__ __align__(16) char As_l[RB * DIM * 2];   // 16 KB
    __shared__ __align__(16) char Bs_h[CT * BK * 2];    // 16 KB
    __shared__ __align__(16) char Bs_l[CT * BK * 2];    // 16 KB

    const int t    = threadIdx.x;
    const int lane = t & 63;
    const int w    = t >> 6;
    const int l15  = lane & 15;
    const int l4   = lane >> 4;
    const int rowbase = blockIdx.x * RB;

    // ---- stage A panel once: 32 rows x 256 depth, split hi / scaled-lo ----
    {
        int r  = t >> 3;           // 0..31
        int d0 = (t & 7) * 32;     // 0..224
        const float* gp = z + (size_t)(rowbase + r) * DIM + d0;
        #pragma unroll
        for (int i = 0; i < 4; ++i) {
            float4 x0 = *(const float4*)(gp + i * 8);
            float4 x1 = *(const float4*)(gp + i * 8 + 4);
            float xs[8] = {x0.x, x0.y, x0.z, x0.w, x1.x, x1.y, x1.z, x1.w};
            f16x8 hi, lo;
            #pragma unroll
            for (int j = 0; j < 8; ++j) {
                f16 h = (f16)xs[j];
                float rr = xs[j] - (float)h;
                hi[j] = h;
                lo[j] = (f16)(rr * LOSCALE);
            }
            int byte = r * 512 + (d0 + i * 8) * 2;
            int sb   = byte ^ ((r & 7) << 4);      // bank-conflict swizzle
            *(f16x8*)(As_h + sb) = hi;
            *(f16x8*)(As_l + sb) = lo;
        }
    }

    unsigned long long best[2][4];
    #pragma unroll
    for (int m = 0; m < 2; ++m)
        #pragma unroll
        for (int q = 0; q < 4; ++q) best[m][q] = ~0ULL;

    __syncthreads();

    for (int ct = 0; ct < 4096; ct += CT) {
        f32x4 acc0[2][2], acc1[2][2];
        #pragma unroll
        for (int m = 0; m < 2; ++m)
            #pragma unroll
            for (int n = 0; n < 2; ++n) {
                f32x4 zz = {0.f, 0.f, 0.f, 0.f};
                acc0[m][n] = zz; acc1[m][n] = zz;
            }

        for (int dc = 0; dc < DIM; dc += BK) {
            __syncthreads();
            // stage B tile: 128 codes x 64 depth, hi+lo (pre-split f16)
            {
                int r     = t >> 1;              // 0..127
                int dpart = (t & 1) * 32;        // 0 / 32
                const f16* gh = eh + (size_t)(ct + r) * DIM + dc + dpart;
                const f16* gl = el + (size_t)(ct + r) * DIM + dc + dpart;
                #pragma unroll
                for (int i = 0; i < 4; ++i) {
                    f16x8 vh = *(const f16x8*)(gh + i * 8);
                    f16x8 vl = *(const f16x8*)(gl + i * 8);
                    int byte = r * 128 + (dpart + i * 8) * 2;
                    int sb   = byte ^ ((r & 7) << 4);
                    *(f16x8*)(Bs_h + sb) = vh;
                    *(f16x8*)(Bs_l + sb) = vl;
                }
            }
            __syncthreads();
            // compute: 2 k-steps x 12 MFMA
            #pragma unroll
            for (int kk = 0; kk < BK; kk += 32) {
                f16x8 ah[2], al[2], bh[2], bl[2];
                #pragma unroll
                for (int m = 0; m < 2; ++m) {
                    int r    = m * 16 + l15;
                    int byte = (r * 512 + (dc + kk + l4 * 8) * 2) ^ ((r & 7) << 4);
                    ah[m] = *(const f16x8*)(As_h + byte);
                    al[m] = *(const f16x8*)(As_l + byte);
                }
                #pragma unroll
                for (int n = 0; n < 2; ++n) {
                    int r    = w * 32 + n * 16 + l15;
                    int byte = (r * 128 + (kk + l4 * 8) * 2) ^ ((r & 7) << 4);
                    bh[n] = *(const f16x8*)(Bs_h + byte);
                    bl[n] = *(const f16x8*)(Bs_l + byte);
                }
                #pragma unroll
                for (int m = 0; m < 2; ++m)
                    #pragma unroll
                    for (int n = 0; n < 2; ++n) {
                        acc0[m][n] = __builtin_amdgcn_mfma_f32_16x16x32_f16(ah[m], bh[n], acc0[m][n], 0, 0, 0);
                        acc1[m][n] = __builtin_amdgcn_mfma_f32_16x16x32_f16(ah[m], bl[n], acc1[m][n], 0, 0, 0);
                        acc1[m][n] = __builtin_amdgcn_mfma_f32_16x16x32_f16(al[m], bh[n], acc1[m][n], 0, 0, 0);
                    }
            }
        }
        // epilogue: fold scales, distances, running argmin
        #pragma unroll
        for (int n = 0; n < 2; ++n) {
            int c = ct + w * 32 + n * 16 + l15;
            float e2c = e2[c];
            #pragma unroll
            for (int m = 0; m < 2; ++m)
                #pragma unroll
                for (int q = 0; q < 4; ++q) {
                    float dot  = acc0[m][n][q] + acc1[m][n][q] * INV_LOSCALE;
                    float dist = e2c - 2.0f * dot;
                    unsigned u   = __float_as_uint(dist);
                    unsigned key = (u & 0x80000000u) ? ~u : (u | 0x80000000u);
                    unsigned long long k64 = ((unsigned long long)key << 32) | (unsigned)c;
                    if (k64 < best[m][q]) best[m][q] = k64;
                }
        }
    }

    // reduce across the 16 column-lanes (same rows: lanes differing in l15)
    #pragma unroll
    for (int m = 0; m < 2; ++m)
        #pragma unroll
        for (int q = 0; q < 4; ++q) {
            unsigned long long b = best[m][q];
            #pragma unroll
            for (int off = 8; off; off >>= 1) {
                unsigned bh_ = (unsigned)(b >> 32), bl_ = (unsigned)b;
                unsigned oh = __shfl_xor(bh_, off), ol = __shfl_xor(bl_, off);
                unsigned long long o = ((unsigned long long)oh << 32) | ol;
                if (o < b) b = o;
            }
            best[m][q] = b;
        }

    __syncthreads();   // safe to reuse Bs_h as reduce buffer now
    unsigned long long* red = (unsigned long long*)Bs_h;   // [4][32]
    if (l15 == 0) {
        #pragma unroll
        for (int m = 0; m < 2; ++m)
            #pragma unroll
            for (int q = 0; q < 4; ++q) {
                int row = m * 16 + l4 * 4 + q;
                red[w * 32 + row] = best[m][q];
            }
    }
    __syncthreads();
    if (t < RB) {
        unsigned long long b = red[t];
        #pragma unroll
        for (int w2 = 1; w2 < 4; ++w2) {
            unsigned long long o = red[w2 * 32 + t];
            if (o < b) b = o;
        }
        idxf[rowbase + t] = (float)(unsigned)(b & 0xffffffffu);
    }
}

// ------------------------- round-1 fallback argmin -------------------------
__global__ __launch_bounds__(256, 2) void vq_argmin_f32(
    const float* __restrict__ z, const float* __restrict__ emb,
    const float* __restrict__ e2, float* __restrict__ idxf, int K)
{
    __shared__ float zs[64 * 36];
    __shared__ float es[128 * 36];
    const int t = threadIdx.x;
    const int tx = t & 15;
    const int ty = t >> 4;
    const int rowbase = blockIdx.x * 64;
    const float* zbase = z + (size_t)rowbase * DIM;
    float best[4]; int bidx[4];
    #pragma unroll
    for (int i = 0; i < 4; ++i) { best[i] = 3.4e38f; bidx[i] = 0; }
    for (int kt = 0; kt < K; kt += 128) {
        float acc[4][8];
        #pragma unroll
        for (int i = 0; i < 4; ++i)
            #pragma unroll
            for (int j = 0; j < 8; ++j) acc[i][j] = 0.0f;
        for (int dc = 0; dc < DIM; dc += 32) {
            { int lr = t >> 2, o = (t & 3) * 8;
              const float* gp = zbase + (size_t)lr * DIM + dc + o;
              *(float4*)&zs[lr*36+o]   = *(const float4*)gp;
              *(float4*)&zs[lr*36+o+4] = *(const float4*)(gp+4); }
            { int lc = t >> 1, o = (t & 1) * 16;
              const float* gp = emb + (size_t)(kt+lc) * DIM + dc + o;
              *(float4*)&es[lc*36+o]    = *(const float4*)gp;
              *(float4*)&es[lc*36+o+4]  = *(const float4*)(gp+4);
              *(float4*)&es[lc*36+o+8]  = *(const float4*)(gp+8);
              *(float4*)&es[lc*36+o+12] = *(const float4*)(gp+12); }
            __syncthreads();
            const float* zp = &zs[(ty*4)*36];
            const float* ep = &es[tx*36];
            #pragma unroll
            for (int d = 0; d < 32; d += 4) {
                float4 zv[4], ev[8];
                #pragma unroll
                for (int i = 0; i < 4; ++i) zv[i] = *(const float4*)&zp[i*36+d];
                #pragma unroll
                for (int j = 0; j < 8; ++j) ev[j] = *(const float4*)&ep[j*16*36+d];
                #pragma unroll
                for (int i = 0; i < 4; ++i)
                    #pragma unroll
                    for (int j = 0; j < 8; ++j) {
                        acc[i][j] += zv[i].x*ev[j].x; acc[i][j] += zv[i].y*ev[j].y;
                        acc[i][j] += zv[i].z*ev[j].z; acc[i][j] += zv[i].w*ev[j].w;
                    }
            }
            __syncthreads();
        }
        #pragma unroll
        for (int j = 0; j < 8; ++j) {
            int c = kt + tx + 16*j;
            float ev2 = e2[c];
            #pragma unroll
            for (int i = 0; i < 4; ++i) {
                float dist = ev2 - 2.0f*acc[i][j];
                if (dist < best[i] || (dist == best[i] && c < bidx[i])) { best[i]=dist; bidx[i]=c; }
            }
        }
    }
    #pragma unroll
    for (int i = 0; i < 4; ++i) {
        float bd = best[i]; int bi = bidx[i];
        #pragma unroll
        for (int off = 8; off; off >>= 1) {
            float od = __shfl_xor(bd, off); int oi = __shfl_xor(bi, off);
            if (od < bd || (od == bd && oi < bi)) { bd = od; bi = oi; }
        }
        if (tx == 0) idxf[rowbase + ty*4 + i] = (float)bi;
    }
}

// ------------------------------ epilogue ops -------------------------------
__global__ void vq_gather(const float* __restrict__ emb,
                          const float* __restrict__ idxf,
                          float* __restrict__ zq, int N)
{
    int n = blockIdx.x * 4 + (threadIdx.x >> 6);
    int l = threadIdx.x & 63;
    if (n >= N) return;
    int idx = (int)idxf[n];
    ((float4*)(zq + (size_t)n * DIM))[l] = ((const float4*)(emb + (size_t)idx * DIM))[l];
}

__global__ void vq_hist(const float* __restrict__ idxf, int* __restrict__ counts, int N) {
    int n = blockIdx.x * blockDim.x + threadIdx.x;
    if (n < N) atomicAdd(&counts[(int)idxf[n]], 1);
}

__global__ void vq_ppl(const int* __restrict__ counts, float invN,
                       float* __restrict__ out, int K)
{
    int t = threadIdx.x;
    float s = 0.0f;
    for (int k = t; k < K; k += 256) {
        float p = (float)counts[k] * invN;
        s += p * logf(p + 1e-10f);
    }
    #pragma unroll
    for (int off = 32; off; off >>= 1) s += __shfl_xor(s, off);
    __shared__ float wsum[4];
    if ((t & 63) == 0) wsum[t >> 6] = s;
    __syncthreads();
    if (t == 0) out[0] = expf(-(wsum[0] + wsum[1] + wsum[2] + wsum[3]));
}

extern "C" void kernel_launch(void* const* d_in, const int* in_sizes, int n_in,
                              void* d_out, int out_size, void* d_ws, size_t ws_size,
                              hipStream_t stream)
{
    const float* z   = (const float*)d_in[0];
    const float* emb = (const float*)d_in[1];
    const int N = in_sizes[0] / DIM;   // 32768
    const int K = in_sizes[1] / DIM;   // 4096

    float* out  = (float*)d_out;
    float* zq   = out;
    float* idxf = out + (size_t)N * DIM;
    float* ppl  = idxf + N;

    const size_t EH_BYTES = (size_t)K * DIM * sizeof(f16);   // 2 MB
    const size_t NEED = 2 * EH_BYTES + 2 * 16384;

    if (ws_size >= NEED) {
        f16*   eh     = (f16*)d_ws;
        f16*   el     = (f16*)((char*)d_ws + EH_BYTES);
        float* e2     = (float*)((char*)d_ws + 2 * EH_BYTES);
        int*   counts = (int*)((char*)d_ws + 2 * EH_BYTES + 16384);

        vq_pack<<<(K * DIM / 8 + 255) / 256, 256, 0, stream>>>(emb, eh, el);
        vq_e2<<<K, 64, 0, stream>>>(emb, e2);
        vq_zero<<<(K + 255) / 256, 256, 0, stream>>>(counts, K);
        vq_argmin2<<<N / RB, 256, 0, stream>>>(z, eh, el, e2, idxf);
        vq_gather<<<N / 4, 256, 0, stream>>>(emb, idxf, zq, N);
        vq_hist<<<(N + 255) / 256, 256, 0, stream>>>(idxf, counts, N);
        vq_ppl<<<1, 256, 0, stream>>>(counts, 1.0f / (float)N, ppl, K);
    } else {
        float* e2     = (float*)d_ws;
        int*   counts = (int*)((char*)d_ws + (size_t)K * sizeof(float));
        vq_e2<<<K, 64, 0, stream>>>(emb, e2);
        vq_zero<<<(K + 255) / 256, 256, 0, stream>>>(counts, K);
        vq_argmin_f32<<<N / 64, 256, 0, stream>>>(z, emb, e2, idxf, K);
        vq_gather<<<N / 4, 256, 0, stream>>>(emb, idxf, zq, N);
        vq_hist<<<(N + 255) / 256, 256, 0, stream>>>(idxf, counts, N);
        vq_ppl<<<1, 256, 0, stream>>>(counts, 1.0f / (float)N, ppl, K);
    }
}

// Round 3
// 297.348 us; speedup vs baseline: 4.3806x; 1.2809x over previous
//
#include <hip/hip_runtime.h>
#include <hip/hip_bf16.h>
#include <math.h>
#include <stdint.h>

typedef _Float16 f16;
typedef _Float16 f16x8 __attribute__((ext_vector_type(8)));
typedef float f32x16 __attribute__((ext_vector_type(16)));

#define DIM 256
#define RB 64       // rows per block
#define CT 128      // codes per tile
#define LOSCALE 2048.0f
#define INV_LOSCALE (1.0f/2048.0f)

#define GLOAD16(gp, lp) __builtin_amdgcn_global_load_lds( \
    (const __attribute__((address_space(1))) void*)(gp),  \
    (__attribute__((address_space(3))) void*)(lp), 16, 0, 0)

// ---------------------------------------------------------------------------
// prep: split embedding into f16 hi + scaled f16 lo (lo' = (e-hi)*2048)
// ---------------------------------------------------------------------------
__global__ void vq_pack(const float* __restrict__ emb,
                        f16* __restrict__ eh, f16* __restrict__ el)
{
    int gid = blockIdx.x * blockDim.x + threadIdx.x;   // one per 8 elements
    int k  = gid >> 5;
    int d0 = (gid & 31) * 8;
    const float* gp = emb + (size_t)k * DIM + d0;
    float4 x0 = *(const float4*)gp;
    float4 x1 = *(const float4*)(gp + 4);
    float xs[8] = {x0.x, x0.y, x0.z, x0.w, x1.x, x1.y, x1.z, x1.w};
    f16x8 hi, lo;
    #pragma unroll
    for (int j = 0; j < 8; ++j) {
        f16 h = (f16)xs[j];
        float r = xs[j] - (float)h;
        hi[j] = h;
        lo[j] = (f16)(r * LOSCALE);
    }
    *(f16x8*)(eh + (size_t)k * DIM + d0) = hi;
    *(f16x8*)(el + (size_t)k * DIM + d0) = lo;
}

// ||e_k||^2, one 64-thread block per code (fp32, full precision)
__global__ void vq_e2(const float* __restrict__ emb, float* __restrict__ e2) {
    int k = blockIdx.x;
    int l = threadIdx.x;
    float4 v = ((const float4*)(emb + (size_t)k * DIM))[l];
    float s = v.x * v.x + v.y * v.y + v.z * v.z + v.w * v.w;
    #pragma unroll
    for (int off = 32; off; off >>= 1) s += __shfl_xor(s, off);
    if (l == 0) e2[k] = s;
}

__global__ void vq_zero(int* __restrict__ p, int n) {
    int i = blockIdx.x * blockDim.x + threadIdx.x;
    if (i < n) p[i] = 0;
}

// ---------------------------------------------------------------------------
// MFMA distance GEMM + fused argmin (32x32x16 f16, A-in-registers).
// 512 thr = 8 waves (2 row-groups x 4 col-groups). RB=64 rows/block.
// Per wave: 32 rows x 32 codes per tile; dual-precision accumulate.
// B double-buffered in LDS via global_load_lds, 1 barrier per 64-depth chunk.
// ---------------------------------------------------------------------------
__global__ __launch_bounds__(512, 2) void vq_argmin2(
    const float* __restrict__ z, const f16* __restrict__ eh,
    const f16* __restrict__ el, const float* __restrict__ e2,
    float* __restrict__ idxf)
{
    __shared__ __align__(16) char lds[65536];        // A panel, then B dbuf
    __shared__ unsigned long long red[4 * RB];       // 2 KB argmin reduce

    const int t    = threadIdx.x;
    const int lane = t & 63;
    const int w    = t >> 6;          // 0..7
    const int wrow = w >> 2;          // 0..1
    const int wcol = w & 3;           // 0..3
    const int l31  = lane & 31;
    const int rowbase = blockIdx.x * RB;

    // ---- stage A panel (64 rows x 256 f32 = 64KB) via global_load_lds ----
    {
        #pragma unroll
        for (int i = 0; i < 8; ++i) {
            int r = w * 8 + i;                       // 0..63
            int soff = (lane * 16) ^ ((r & 7) << 4); // pre-swizzled source
            const float* gp = z + (size_t)(rowbase + r) * DIM + (soff >> 2);
            GLOAD16(gp, lds + r * 1024);
        }
    }
    __syncthreads();

    // ---- A frags to registers: 16 k-steps x (hi,lo) ----
    f16x8 a_h[16], a_l[16];
    {
        int row = wrow * 32 + l31;
        const char* abase = lds + row * 1024;
        int swz = (row & 7) << 4;
        #pragma unroll
        for (int s = 0; s < 16; ++s) {
            int b0 = s * 64 + (lane >> 5) * 32;
            float4 x0 = *(const float4*)(abase + ((b0)      ^ swz));
            float4 x1 = *(const float4*)(abase + ((b0 + 16) ^ swz));
            float xs[8] = {x0.x, x0.y, x0.z, x0.w, x1.x, x1.y, x1.z, x1.w};
            #pragma unroll
            for (int j = 0; j < 8; ++j) {
                f16 h = (f16)xs[j];
                a_h[s][j] = h;
                a_l[s][j] = (f16)((xs[j] - (float)h) * LOSCALE);
            }
        }
    }
    __syncthreads();   // all waves done reading A before B staging reuses lds

    unsigned long long best[16];
    #pragma unroll
    for (int q = 0; q < 16; ++q) best[q] = ~0ULL;

    // ---- stage B chunk 0 (tile 0, depth 0..63) into buf0 ----
    {
        #pragma unroll
        for (int i = 0; i < 4; ++i) {
            int idx  = w * 4 + i;        // 0..31
            int half = idx >> 4;         // 0:hi 1:lo
            int rg   = (idx & 15) * 8;
            int r    = rg + (lane >> 3);
            int soff = ((lane & 7) * 16) ^ ((r & 7) << 4);
            const f16* g = (half ? el : eh) + (size_t)r * DIM + (soff >> 1);
            GLOAD16(g, lds + half * 16384 + (idx & 15) * 1024);
        }
    }

    const int brow = wcol * 32 + l31;
    const int bswz = (brow & 7) << 4;

    for (int ti = 0; ti < 32; ++ti) {
        const int ct = ti * CT;
        f32x16 acc0, acc1;
        #pragma unroll
        for (int q = 0; q < 16; ++q) { acc0[q] = 0.0f; acc1[q] = 0.0f; }
        float e2c = e2[ct + wcol * 32 + l31];

        #pragma unroll
        for (int dc = 0; dc < 4; ++dc) {
            __syncthreads();   // drains vmcnt: buf[dc&1] staged; buf[dc&1^1] free

            // stage next chunk into the other buffer
            if (!(ti == 31 && dc == 3)) {
                const int nct = (dc == 3) ? ct + CT : ct;
                const int nd  = ((dc + 1) & 3) * 64;
                char* nb = lds + (((dc + 1) & 1) * 32768);
                #pragma unroll
                for (int i = 0; i < 4; ++i) {
                    int idx  = w * 4 + i;
                    int half = idx >> 4;
                    int rg   = (idx & 15) * 8;
                    int r    = rg + (lane >> 3);
                    int soff = ((lane & 7) * 16) ^ ((r & 7) << 4);
                    const f16* g = (half ? el : eh)
                                 + (size_t)(nct + r) * DIM + nd + (soff >> 1);
                    GLOAD16(g, nb + half * 16384 + (idx & 15) * 1024);
                }
            }

            // compute current chunk: 4 k-steps x {2 ds_read_b128, 3 MFMA}
            const char* bb = lds + ((dc & 1) * 32768);
            #pragma unroll
            for (int kk = 0; kk < 4; ++kk) {
                const int s = dc * 4 + kk;   // static A index
                int boff = (kk * 32 + (lane >> 5) * 16) ^ bswz;
                f16x8 bh = *(const f16x8*)(bb + brow * 128 + boff);
                f16x8 bl = *(const f16x8*)(bb + 16384 + brow * 128 + boff);
                acc0 = __builtin_amdgcn_mfma_f32_32x32x16_f16(a_h[s], bh, acc0, 0, 0, 0);
                acc1 = __builtin_amdgcn_mfma_f32_32x32x16_f16(a_h[s], bl, acc1, 0, 0, 0);
                acc1 = __builtin_amdgcn_mfma_f32_32x32x16_f16(a_l[s], bh, acc1, 0, 0, 0);
            }
        }

        // epilogue: distances + running argmin (code c fixed per lane)
        const unsigned c = (unsigned)(ct + wcol * 32 + l31);
        #pragma unroll
        for (int q = 0; q < 16; ++q) {
            float dot  = acc0[q] + acc1[q] * INV_LOSCALE;
            float dist = e2c - 2.0f * dot;
            unsigned u   = __float_as_uint(dist);
            unsigned key = u ^ (unsigned)(((int)u >> 31) | 0x80000000);
            unsigned long long k64 = ((unsigned long long)key << 32) | c;
            if (k64 < best[q]) best[q] = k64;
        }
    }

    // ---- reduce across the 32 code-lanes (offsets <32 keep lane>>5) ----
    #pragma unroll
    for (int q = 0; q < 16; ++q) {
        unsigned long long b = best[q];
        #pragma unroll
        for (int off = 16; off; off >>= 1) {
            unsigned hi_ = __shfl_xor((unsigned)(b >> 32), off);
            unsigned lo_ = __shfl_xor((unsigned)b, off);
            unsigned long long o = ((unsigned long long)hi_ << 32) | lo_;
            if (o < b) b = o;
        }
        best[q] = b;
    }

    if (l31 == 0) {   // lanes 0 and 32 hold disjoint row-sets
        #pragma unroll
        for (int q = 0; q < 16; ++q) {
            int row = wrow * 32 + (q & 3) + 8 * (q >> 2) + 4 * (lane >> 5);
            red[wcol * RB + row] = best[q];
        }
    }
    __syncthreads();
    if (t < RB) {
        unsigned long long b = red[t];
        #pragma unroll
        for (int wc = 1; wc < 4; ++wc) {
            unsigned long long o = red[wc * RB + t];
            if (o < b) b = o;
        }
        idxf[rowbase + t] = (float)(unsigned)(b & 0xffffffffu);
    }
}

// ------------------------- round-1 fallback argmin -------------------------
__global__ __launch_bounds__(256, 2) void vq_argmin_f32(
    const float* __restrict__ z, const float* __restrict__ emb,
    const float* __restrict__ e2, float* __restrict__ idxf, int K)
{
    __shared__ float zs[64 * 36];
    __shared__ float es[128 * 36];
    const int t = threadIdx.x;
    const int tx = t & 15;
    const int ty = t >> 4;
    const int rowbase = blockIdx.x * 64;
    const float* zbase = z + (size_t)rowbase * DIM;
    float best[4]; int bidx[4];
    #pragma unroll
    for (int i = 0; i < 4; ++i) { best[i] = 3.4e38f; bidx[i] = 0; }
    for (int kt = 0; kt < K; kt += 128) {
        float acc[4][8];
        #pragma unroll
        for (int i = 0; i < 4; ++i)
            #pragma unroll
            for (int j = 0; j < 8; ++j) acc[i][j] = 0.0f;
        for (int dc = 0; dc < DIM; dc += 32) {
            { int lr = t >> 2, o = (t & 3) * 8;
              const float* gp = zbase + (size_t)lr * DIM + dc + o;
              *(float4*)&zs[lr*36+o]   = *(const float4*)gp;
              *(float4*)&zs[lr*36+o+4] = *(const float4*)(gp+4); }
            { int lc = t >> 1, o = (t & 1) * 16;
              const float* gp = emb + (size_t)(kt+lc) * DIM + dc + o;
              *(float4*)&es[lc*36+o]    = *(const float4*)gp;
              *(float4*)&es[lc*36+o+4]  = *(const float4*)(gp+4);
              *(float4*)&es[lc*36+o+8]  = *(const float4*)(gp+8);
              *(float4*)&es[lc*36+o+12] = *(const float4*)(gp+12); }
            __syncthreads();
            const float* zp = &zs[(ty*4)*36];
            const float* ep = &es[tx*36];
            #pragma unroll
            for (int d = 0; d < 32; d += 4) {
                float4 zv[4], ev[8];
                #pragma unroll
                for (int i = 0; i < 4; ++i) zv[i] = *(const float4*)&zp[i*36+d];
                #pragma unroll
                for (int j = 0; j < 8; ++j) ev[j] = *(const float4*)&ep[j*16*36+d];
                #pragma unroll
                for (int i = 0; i < 4; ++i)
                    #pragma unroll
                    for (int j = 0; j < 8; ++j) {
                        acc[i][j] += zv[i].x*ev[j].x; acc[i][j] += zv[i].y*ev[j].y;
                        acc[i][j] += zv[i].z*ev[j].z; acc[i][j] += zv[i].w*ev[j].w;
                    }
            }
            __syncthreads();
        }
        #pragma unroll
        for (int j = 0; j < 8; ++j) {
            int c = kt + tx + 16*j;
            float ev2 = e2[c];
            #pragma unroll
            for (int i = 0; i < 4; ++i) {
                float dist = ev2 - 2.0f*acc[i][j];
                if (dist < best[i] || (dist == best[i] && c < bidx[i])) { best[i]=dist; bidx[i]=c; }
            }
        }
    }
    #pragma unroll
    for (int i = 0; i < 4; ++i) {
        float bd = best[i]; int bi = bidx[i];
        #pragma unroll
        for (int off = 8; off; off >>= 1) {
            float od = __shfl_xor(bd, off); int oi = __shfl_xor(bi, off);
            if (od < bd || (od == bd && oi < bi)) { bd = od; bi = oi; }
        }
        if (tx == 0) idxf[rowbase + ty*4 + i] = (float)bi;
    }
}

// ------------------------------ epilogue ops -------------------------------
__global__ void vq_gather(const float* __restrict__ emb,
                          const float* __restrict__ idxf,
                          float* __restrict__ zq, int N)
{
    int n = blockIdx.x * 4 + (threadIdx.x >> 6);
    int l = threadIdx.x & 63;
    if (n >= N) return;
    int idx = (int)idxf[n];
    ((float4*)(zq + (size_t)n * DIM))[l] = ((const float4*)(emb + (size_t)idx * DIM))[l];
}

__global__ void vq_hist(const float* __restrict__ idxf, int* __restrict__ counts, int N) {
    int n = blockIdx.x * blockDim.x + threadIdx.x;
    if (n < N) atomicAdd(&counts[(int)idxf[n]], 1);
}

__global__ void vq_ppl(const int* __restrict__ counts, float invN,
                       float* __restrict__ out, int K)
{
    int t = threadIdx.x;
    float s = 0.0f;
    for (int k = t; k < K; k += 256) {
        float p = (float)counts[k] * invN;
        s += p * logf(p + 1e-10f);
    }
    #pragma unroll
    for (int off = 32; off; off >>= 1) s += __shfl_xor(s, off);
    __shared__ float wsum[4];
    if ((t & 63) == 0) wsum[t >> 6] = s;
    __syncthreads();
    if (t == 0) out[0] = expf(-(wsum[0] + wsum[1] + wsum[2] + wsum[3]));
}

extern "C" void kernel_launch(void* const* d_in, const int* in_sizes, int n_in,
                              void* d_out, int out_size, void* d_ws, size_t ws_size,
                              hipStream_t stream)
{
    const float* z   = (const float*)d_in[0];
    const float* emb = (const float*)d_in[1];
    const int N = in_sizes[0] / DIM;   // 32768
    const int K = in_sizes[1] / DIM;   // 4096

    float* out  = (float*)d_out;
    float* zq   = out;
    float* idxf = out + (size_t)N * DIM;
    float* ppl  = idxf + N;

    const size_t EH_BYTES = (size_t)K * DIM * sizeof(f16);   // 2 MB
    const size_t NEED = 2 * EH_BYTES + 2 * 16384;

    if (ws_size >= NEED) {
        f16*   eh     = (f16*)d_ws;
        f16*   el     = (f16*)((char*)d_ws + EH_BYTES);
        float* e2     = (float*)((char*)d_ws + 2 * EH_BYTES);
        int*   counts = (int*)((char*)d_ws + 2 * EH_BYTES + 16384);

        vq_pack<<<(K * DIM / 8 + 255) / 256, 256, 0, stream>>>(emb, eh, el);
        vq_e2<<<K, 64, 0, stream>>>(emb, e2);
        vq_zero<<<(K + 255) / 256, 256, 0, stream>>>(counts, K);
        vq_argmin2<<<N / RB, 512, 0, stream>>>(z, eh, el, e2, idxf);
        vq_gather<<<N / 4, 256, 0, stream>>>(emb, idxf, zq, N);
        vq_hist<<<(N + 255) / 256, 256, 0, stream>>>(idxf, counts, N);
        vq_ppl<<<1, 256, 0, stream>>>(counts, 1.0f / (float)N, ppl, K);
    } else {
        float* e2     = (float*)d_ws;
        int*   counts = (int*)((char*)d_ws + (size_t)K * sizeof(float));
        vq_e2<<<K, 64, 0, stream>>>(emb, e2);
        vq_zero<<<(K + 255) / 256, 256, 0, stream>>>(counts, K);
        vq_argmin_f32<<<N / 64, 256, 0, stream>>>(z, emb, e2, idxf, K);
        vq_gather<<<N / 4, 256, 0, stream>>>(emb, idxf, zq, N);
        vq_hist<<<(N + 255) / 256, 256, 0, stream>>>(idxf, counts, N);
        vq_ppl<<<1, 256, 0, stream>>>(counts, 1.0f / (float)N, ppl, K);
    }
}